// Round 1
// baseline (1434.639 us; speedup 1.0000x reference)
//
#include <hip/hip_runtime.h>
#include <stdint.h>

// Problem dims (fixed by the reference): H=8 heads, D=64.
#define HD 8
#define DD 64

// Monotone float->uint mapping so a single unsigned atomicMax implements float max.
__device__ __forceinline__ unsigned fmap(float f) {
    unsigned u = __float_as_uint(f);
    return u ^ (unsigned)(((int)u >> 31) | 0x80000000);
}
__device__ __forceinline__ float funmap(unsigned u) {
    u ^= ((int)u < 0) ? 0x80000000u : 0xFFFFFFFFu;
    return __uint_as_float(u);
}
// fmap(-inf) = 0x007FFFFF : the identity element for the mapped max.
#define FMAP_NEG_INF 0x007FFFFFu

// Phase A: t[n*8+h] = tanh(sum_d X[n,h,d] * W[d,h]); init m_u[n*8+h] = mapped(-inf).
// One wave (64 lanes) per node: 2 x float4 per lane covers the node's 512 floats.
__global__ __launch_bounds__(256) void attn_tanh_kernel(
    const float* __restrict__ X, const float* __restrict__ Wk,
    float* __restrict__ t, unsigned* __restrict__ m_u, int N)
{
    __shared__ float Ws[DD * HD];   // W[d*8+h], 2 KB
    int tid = threadIdx.x;
    for (int i = tid; i < DD * HD; i += 256) Ws[i] = Wk[i];
    __syncthreads();

    int wave = tid >> 6, lane = tid & 63;
    int node = blockIdx.x * 4 + wave;
    if (node >= N) return;

    const float4* X4 = (const float4*)X + (size_t)node * 128;  // 512 floats/node
    float p0, p1;
    {
        int idx = lane;                       // floats [idx*4 .. idx*4+3], h = idx/16
        float4 xv = X4[idx];
        int h = idx >> 4, d0 = (idx & 15) << 2;
        p0 = xv.x * Ws[(d0 + 0) * HD + h] + xv.y * Ws[(d0 + 1) * HD + h]
           + xv.z * Ws[(d0 + 2) * HD + h] + xv.w * Ws[(d0 + 3) * HD + h];
    }
    {
        int idx = 64 + lane;                  // h = 4 + lane/16
        float4 xv = X4[idx];
        int h = idx >> 4, d0 = (idx & 15) << 2;
        p1 = xv.x * Ws[(d0 + 0) * HD + h] + xv.y * Ws[(d0 + 1) * HD + h]
           + xv.z * Ws[(d0 + 2) * HD + h] + xv.w * Ws[(d0 + 3) * HD + h];
    }
    // Reduce within each group of 16 lanes (xor 8,4,2,1 stays inside the group).
    for (int off = 8; off; off >>= 1) {
        p0 += __shfl_xor(p0, off);
        p1 += __shfl_xor(p1, off);
    }
    if ((lane & 15) == 0) {
        int g = lane >> 4;                    // head group 0..3
        size_t base = (size_t)node * HD;
        t[base + g]      = tanhf(p0);         // h = g     (iter 0)
        t[base + 4 + g]  = tanhf(p1);         // h = 4 + g (iter 1)
        m_u[base + g]     = FMAP_NEG_INF;
        m_u[base + 4 + g] = FMAP_NEG_INF;
    }
}

// Phase B: per-edge segment max: m[tgt[e],h] = max over edges of t[src[e],h].
__global__ __launch_bounds__(256) void seg_max_kernel(
    const int* __restrict__ sources, const int* __restrict__ targets,
    const float* __restrict__ t, unsigned* __restrict__ m_u, int E)
{
    int e = blockIdx.x * 256 + threadIdx.x;
    if (e >= E) return;
    int s  = sources[e];
    int tg = targets[e];
    const float4* t4 = (const float4*)t;
    float4 a = t4[(size_t)s * 2];
    float4 b = t4[(size_t)s * 2 + 1];
    unsigned* mp = m_u + (size_t)tg * HD;
    atomicMax(mp + 0, fmap(a.x));
    atomicMax(mp + 1, fmap(a.y));
    atomicMax(mp + 2, fmap(a.z));
    atomicMax(mp + 3, fmap(a.w));
    atomicMax(mp + 4, fmap(b.x));
    atomicMax(mp + 5, fmap(b.y));
    atomicMax(mp + 6, fmap(b.z));
    atomicMax(mp + 7, fmap(b.w));
}

// Phase C: out[e,h] = exp(t[src,h] - m[tgt,h]) * drop_mask[e,h].
// (The reference's s = segment_max(exp(ef-m)) + 1e-9 == 1.0f exactly in fp32.)
__global__ __launch_bounds__(256) void finalize_kernel(
    const int* __restrict__ sources, const int* __restrict__ targets,
    const float* __restrict__ t, const unsigned* __restrict__ m_u,
    const float* __restrict__ dm, float* __restrict__ out, int E)
{
    int e = blockIdx.x * 256 + threadIdx.x;
    if (e >= E) return;
    int s  = sources[e];
    int tg = targets[e];
    const float4* t4 = (const float4*)t;
    float4 a = t4[(size_t)s * 2];
    float4 b = t4[(size_t)s * 2 + 1];
    const uint4* m4 = (const uint4*)m_u;
    uint4 mu0 = m4[(size_t)tg * 2];
    uint4 mu1 = m4[(size_t)tg * 2 + 1];
    const float4* dm4 = (const float4*)dm;
    float4 d0 = dm4[(size_t)e * 2];
    float4 d1 = dm4[(size_t)e * 2 + 1];
    float4 o0, o1;
    o0.x = expf(a.x - funmap(mu0.x)) * d0.x;
    o0.y = expf(a.y - funmap(mu0.y)) * d0.y;
    o0.z = expf(a.z - funmap(mu0.z)) * d0.z;
    o0.w = expf(a.w - funmap(mu0.w)) * d0.w;
    o1.x = expf(b.x - funmap(mu1.x)) * d1.x;
    o1.y = expf(b.y - funmap(mu1.y)) * d1.y;
    o1.z = expf(b.z - funmap(mu1.z)) * d1.z;
    o1.w = expf(b.w - funmap(mu1.w)) * d1.w;
    float4* out4 = (float4*)out;
    out4[(size_t)e * 2]     = o0;
    out4[(size_t)e * 2 + 1] = o1;
}

extern "C" void kernel_launch(void* const* d_in, const int* in_sizes, int n_in,
                              void* d_out, int out_size, void* d_ws, size_t ws_size,
                              hipStream_t stream)
{
    const float* X       = (const float*)d_in[0];   // (B,N,H,D) fp32
    const float* Wk      = (const float*)d_in[1];   // (D,H,1)   fp32
    const int*   targets = (const int*)d_in[2];     // (B,E)
    const int*   sources = (const int*)d_in[3];     // (B,E)
    // d_in[4] = degree (unused by the reference math)
    const float* dm      = (const float*)d_in[5];   // (B,E,H)
    // d_in[6] = N scalar (device); use in_sizes instead.

    int E = in_sizes[2];          // B=1
    int N = in_sizes[4];          // degree is (B,N)

    float*    t   = (float*)d_ws;                        // N*8 floats
    unsigned* m_u = (unsigned*)d_ws + (size_t)N * HD;    // N*8 uints

    float* out = (float*)d_out;

    int blocksA = (N + 3) / 4;           // 4 waves/block, 1 wave/node
    attn_tanh_kernel<<<blocksA, 256, 0, stream>>>(X, Wk, t, m_u, N);

    int blocksE = (E + 255) / 256;
    seg_max_kernel<<<blocksE, 256, 0, stream>>>(sources, targets, t, m_u, E);
    finalize_kernel<<<blocksE, 256, 0, stream>>>(sources, targets, t, m_u, dm, out, E);
}

// Round 2
// 661.455 us; speedup vs baseline: 2.1689x; 2.1689x over previous
//
#include <hip/hip_runtime.h>
#include <stdint.h>

// Problem dims (fixed by the reference): H=8 heads, D=64.
#define HD 8
#define DD 64

// Monotone float->uint mapping so a single unsigned atomicMax implements float max.
__device__ __forceinline__ unsigned fmap(float f) {
    unsigned u = __float_as_uint(f);
    return u ^ (unsigned)(((int)u >> 31) | 0x80000000);
}
__device__ __forceinline__ float funmap(unsigned u) {
    u ^= ((int)u < 0) ? 0x80000000u : 0xFFFFFFFFu;
    return __uint_as_float(u);
}
// fmap(-inf) = 0x007FFFFF : the identity element for the mapped max.
#define FMAP_NEG_INF 0x007FFFFFu

// Phase A: t[n*8+h] = tanh(sum_d X[n,h,d] * W[d,h]); init m_u[n*8+h] = mapped(-inf).
// One wave (64 lanes) per node: 2 x float4 per lane covers the node's 512 floats.
__global__ __launch_bounds__(256) void attn_tanh_kernel(
    const float* __restrict__ X, const float* __restrict__ Wk,
    float* __restrict__ t, unsigned* __restrict__ m_u, int N)
{
    __shared__ float Ws[DD * HD];   // W[d*8+h], 2 KB
    int tid = threadIdx.x;
    for (int i = tid; i < DD * HD; i += 256) Ws[i] = Wk[i];
    __syncthreads();

    int wave = tid >> 6, lane = tid & 63;
    int node = blockIdx.x * 4 + wave;
    if (node >= N) return;

    const float4* X4 = (const float4*)X + (size_t)node * 128;  // 512 floats/node
    float p0, p1;
    {
        int idx = lane;                       // floats [idx*4 .. idx*4+3], h = idx/16
        float4 xv = X4[idx];
        int h = idx >> 4, d0 = (idx & 15) << 2;
        p0 = xv.x * Ws[(d0 + 0) * HD + h] + xv.y * Ws[(d0 + 1) * HD + h]
           + xv.z * Ws[(d0 + 2) * HD + h] + xv.w * Ws[(d0 + 3) * HD + h];
    }
    {
        int idx = 64 + lane;                  // h = 4 + lane/16
        float4 xv = X4[idx];
        int h = idx >> 4, d0 = (idx & 15) << 2;
        p1 = xv.x * Ws[(d0 + 0) * HD + h] + xv.y * Ws[(d0 + 1) * HD + h]
           + xv.z * Ws[(d0 + 2) * HD + h] + xv.w * Ws[(d0 + 3) * HD + h];
    }
    // Reduce within each group of 16 lanes (xor 8,4,2,1 stays inside the group).
    for (int off = 8; off; off >>= 1) {
        p0 += __shfl_xor(p0, off);
        p1 += __shfl_xor(p1, off);
    }
    if ((lane & 15) == 0) {
        int g = lane >> 4;                    // head group 0..3
        size_t base = (size_t)node * HD;
        t[base + g]      = tanhf(p0);         // h = g     (iter 0)
        t[base + 4 + g]  = tanhf(p1);         // h = 4 + g (iter 1)
        m_u[base + g]     = FMAP_NEG_INF;
        m_u[base + 4 + g] = FMAP_NEG_INF;
    }
}

// Phase B: per-edge segment max: m[tgt[e],h] = max over edges of t[src[e],h].
// Read-compare-then-atomic: a plain load returns some previously-written value,
// so local <= read implies the final max already covers us -> skip the atomic.
// Stale-low reads only cause redundant atomics, never missed updates.
__global__ __launch_bounds__(256) void seg_max_kernel(
    const int* __restrict__ sources, const int* __restrict__ targets,
    const float* __restrict__ t, unsigned* __restrict__ m_u, int E)
{
    int e = blockIdx.x * 256 + threadIdx.x;
    if (e >= E) return;
    int s  = sources[e];
    int tg = targets[e];
    const float4* t4 = (const float4*)t;
    float4 a = t4[(size_t)s * 2];
    float4 b = t4[(size_t)s * 2 + 1];
    unsigned* mp = m_u + (size_t)tg * HD;
    const uint4* m4 = (const uint4*)mp;
    uint4 c0 = m4[0];
    uint4 c1 = m4[1];
    unsigned f;
    f = fmap(a.x); if (f > c0.x) atomicMax(mp + 0, f);
    f = fmap(a.y); if (f > c0.y) atomicMax(mp + 1, f);
    f = fmap(a.z); if (f > c0.z) atomicMax(mp + 2, f);
    f = fmap(a.w); if (f > c0.w) atomicMax(mp + 3, f);
    f = fmap(b.x); if (f > c1.x) atomicMax(mp + 4, f);
    f = fmap(b.y); if (f > c1.y) atomicMax(mp + 5, f);
    f = fmap(b.z); if (f > c1.z) atomicMax(mp + 6, f);
    f = fmap(b.w); if (f > c1.w) atomicMax(mp + 7, f);
}

// Phase C: out[e,h] = exp(t[src,h] - m[tgt,h]) * drop_mask[e,h].
// (The reference's s = segment_max(exp(ef-m)) + 1e-9 == 1.0f exactly in fp32.)
__global__ __launch_bounds__(256) void finalize_kernel(
    const int* __restrict__ sources, const int* __restrict__ targets,
    const float* __restrict__ t, const unsigned* __restrict__ m_u,
    const float* __restrict__ dm, float* __restrict__ out, int E)
{
    int e = blockIdx.x * 256 + threadIdx.x;
    if (e >= E) return;
    int s  = sources[e];
    int tg = targets[e];
    const float4* t4 = (const float4*)t;
    float4 a = t4[(size_t)s * 2];
    float4 b = t4[(size_t)s * 2 + 1];
    const uint4* m4 = (const uint4*)m_u;
    uint4 mu0 = m4[(size_t)tg * 2];
    uint4 mu1 = m4[(size_t)tg * 2 + 1];
    const float4* dm4 = (const float4*)dm;
    float4 d0 = dm4[(size_t)e * 2];
    float4 d1 = dm4[(size_t)e * 2 + 1];
    float4 o0, o1;
    o0.x = expf(a.x - funmap(mu0.x)) * d0.x;
    o0.y = expf(a.y - funmap(mu0.y)) * d0.y;
    o0.z = expf(a.z - funmap(mu0.z)) * d0.z;
    o0.w = expf(a.w - funmap(mu0.w)) * d0.w;
    o1.x = expf(b.x - funmap(mu1.x)) * d1.x;
    o1.y = expf(b.y - funmap(mu1.y)) * d1.y;
    o1.z = expf(b.z - funmap(mu1.z)) * d1.z;
    o1.w = expf(b.w - funmap(mu1.w)) * d1.w;
    float4* out4 = (float4*)out;
    out4[(size_t)e * 2]     = o0;
    out4[(size_t)e * 2 + 1] = o1;
}

extern "C" void kernel_launch(void* const* d_in, const int* in_sizes, int n_in,
                              void* d_out, int out_size, void* d_ws, size_t ws_size,
                              hipStream_t stream)
{
    const float* X       = (const float*)d_in[0];   // (B,N,H,D) fp32
    const float* Wk      = (const float*)d_in[1];   // (D,H,1)   fp32
    const int*   targets = (const int*)d_in[2];     // (B,E)
    const int*   sources = (const int*)d_in[3];     // (B,E)
    // d_in[4] = degree (unused by the reference math)
    const float* dm      = (const float*)d_in[5];   // (B,E,H)
    // d_in[6] = N scalar (device); use in_sizes instead.

    int E = in_sizes[2];          // B=1
    int N = in_sizes[4];          // degree is (B,N)

    float*    t   = (float*)d_ws;                        // N*8 floats
    unsigned* m_u = (unsigned*)d_ws + (size_t)N * HD;    // N*8 uints

    float* out = (float*)d_out;

    int blocksA = (N + 3) / 4;           // 4 waves/block, 1 wave/node
    attn_tanh_kernel<<<blocksA, 256, 0, stream>>>(X, Wk, t, m_u, N);

    int blocksE = (E + 255) / 256;
    seg_max_kernel<<<blocksE, 256, 0, stream>>>(sources, targets, t, m_u, E);
    finalize_kernel<<<blocksE, 256, 0, stream>>>(sources, targets, t, m_u, dm, out, E);
}

// Round 4
// 639.926 us; speedup vs baseline: 2.2419x; 1.0336x over previous
//
#include <hip/hip_runtime.h>
#include <stdint.h>

#define HD 8
#define DD 64

// Native clang vector types — required by __builtin_nontemporal_load/store.
typedef float  vf4 __attribute__((ext_vector_type(4)));
typedef unsigned vu4 __attribute__((ext_vector_type(4)));

// Monotone float->uint mapping so unsigned atomicMax implements float max.
__device__ __forceinline__ unsigned fmap(float f) {
    unsigned u = __float_as_uint(f);
    return u ^ (unsigned)(((int)u >> 31) | 0x80000000);
}
__device__ __forceinline__ float funmap(unsigned u) {
    u ^= ((int)u < 0) ? 0x80000000u : 0xFFFFFFFFu;
    return __uint_as_float(u);
}
#define FMAP_NEG_INF 0x007FFFFFu

// bf16 helpers. Slot layout per node (4 u32 words): word g = (bf16 h=g) | (bf16 h=g+4)<<16.
__device__ __forceinline__ unsigned pack_bf16_rne(float a, float b) {
    unsigned ua = __float_as_uint(a); ua += 0x7FFF + ((ua >> 16) & 1);
    unsigned ub = __float_as_uint(b); ub += 0x7FFF + ((ub >> 16) & 1);
    return (ua >> 16) | (ub & 0xFFFF0000u);
}
__device__ __forceinline__ float bf_lo(unsigned u) { return __uint_as_float(u << 16); }
__device__ __forceinline__ float bf_hi(unsigned u) { return __uint_as_float(u & 0xFFFF0000u); }

// Phase A: t_pk[n] = packed bf16 tanh(X[n,h,:] . W[:,h]); init m_u slots to mapped(-inf).
// One wave per 2 nodes: 4 independent float4 loads in flight per lane.
__global__ __launch_bounds__(256) void attn_tanh_kernel(
    const float* __restrict__ X, const float* __restrict__ Wk,
    unsigned* __restrict__ t_pk, uint2* __restrict__ m_init, int N)
{
    __shared__ float Ws[DD * HD];   // W[d*8+h], 2 KB
    int tid = threadIdx.x;
    for (int i = tid; i < DD * HD; i += 256) Ws[i] = Wk[i];
    __syncthreads();

    int wave = tid >> 6, lane = tid & 63;
    int n0 = (blockIdx.x * 4 + wave) * 2;
    if (n0 >= N) return;
    bool two = (n0 + 1 < N);

    const vf4* Xa = (const vf4*)X + (size_t)n0 * 128;  // 512 floats/node
    vf4 z = {0.f, 0.f, 0.f, 0.f};
    vf4 xv0 = __builtin_nontemporal_load(Xa + lane);
    vf4 xv1 = __builtin_nontemporal_load(Xa + 64 + lane);
    vf4 xv2 = two ? __builtin_nontemporal_load(Xa + 128 + lane) : z;
    vf4 xv3 = two ? __builtin_nontemporal_load(Xa + 192 + lane) : z;

    int h0 = lane >> 4, d0 = (lane & 15) << 2;
    int h1 = 4 + h0;
    float w00 = Ws[(d0 + 0) * HD + h0], w01 = Ws[(d0 + 1) * HD + h0],
          w02 = Ws[(d0 + 2) * HD + h0], w03 = Ws[(d0 + 3) * HD + h0];
    float w10 = Ws[(d0 + 0) * HD + h1], w11 = Ws[(d0 + 1) * HD + h1],
          w12 = Ws[(d0 + 2) * HD + h1], w13 = Ws[(d0 + 3) * HD + h1];

    float p0 = xv0.x * w00 + xv0.y * w01 + xv0.z * w02 + xv0.w * w03;
    float p1 = xv1.x * w10 + xv1.y * w11 + xv1.z * w12 + xv1.w * w13;
    float p2 = xv2.x * w00 + xv2.y * w01 + xv2.z * w02 + xv2.w * w03;
    float p3 = xv3.x * w10 + xv3.y * w11 + xv3.z * w12 + xv3.w * w13;

    for (int off = 8; off; off >>= 1) {
        p0 += __shfl_xor(p0, off);
        p1 += __shfl_xor(p1, off);
        p2 += __shfl_xor(p2, off);
        p3 += __shfl_xor(p3, off);
    }
    if ((lane & 15) == 0) {
        int g = lane >> 4;
        t_pk[(size_t)n0 * 4 + g] = pack_bf16_rne(tanhf(p0), tanhf(p1));
        m_init[(size_t)n0 * 4 + g] = make_uint2(FMAP_NEG_INF, FMAP_NEG_INF);
        if (two) {
            t_pk[(size_t)(n0 + 1) * 4 + g] = pack_bf16_rne(tanhf(p2), tanhf(p3));
            m_init[(size_t)(n0 + 1) * 4 + g] = make_uint2(FMAP_NEG_INF, FMAP_NEG_INF);
        }
    }
}

// Phase B: m_u[tgt, slot] = max over edges of t[src, slot] (slot order = packed order:
// slots 2g = head g, 2g+1 = head g+4). Read-compare-then-atomic to skip losers.
__global__ __launch_bounds__(256) void seg_max_kernel(
    const int* __restrict__ sources, const int* __restrict__ targets,
    const uint4* __restrict__ t_pk4, unsigned* __restrict__ m_u, int E)
{
    int e = blockIdx.x * 256 + threadIdx.x;
    if (e >= E) return;
    int s  = __builtin_nontemporal_load(sources + e);
    int tg = __builtin_nontemporal_load(targets + e);
    uint4 tv = t_pk4[s];
    unsigned* mp = m_u + (size_t)tg * HD;
    const uint4* m4 = (const uint4*)mp;
    uint4 c0 = m4[0];
    uint4 c1 = m4[1];
    unsigned f;
    f = fmap(bf_lo(tv.x)); if (f > c0.x) atomicMax(mp + 0, f);
    f = fmap(bf_hi(tv.x)); if (f > c0.y) atomicMax(mp + 1, f);
    f = fmap(bf_lo(tv.y)); if (f > c0.z) atomicMax(mp + 2, f);
    f = fmap(bf_hi(tv.y)); if (f > c0.w) atomicMax(mp + 3, f);
    f = fmap(bf_lo(tv.z)); if (f > c1.x) atomicMax(mp + 4, f);
    f = fmap(bf_hi(tv.z)); if (f > c1.y) atomicMax(mp + 5, f);
    f = fmap(bf_lo(tv.w)); if (f > c1.z) atomicMax(mp + 6, f);
    f = fmap(bf_hi(tv.w)); if (f > c1.w) atomicMax(mp + 7, f);
}

// Pack m (fp32-mapped) -> bf16 slots. Lossless: m is a max of bf16 values.
__global__ __launch_bounds__(256) void pack_m_kernel(
    const unsigned* __restrict__ m_u, uint4* __restrict__ m_pk, int N)
{
    int n = blockIdx.x * 256 + threadIdx.x;
    if (n >= N) return;
    const uint4* mu4 = (const uint4*)m_u + (size_t)n * 2;
    uint4 c0 = mu4[0];
    uint4 c1 = mu4[1];
    uint4 o;
    o.x = (__float_as_uint(funmap(c0.x)) >> 16) | (__float_as_uint(funmap(c0.y)) & 0xFFFF0000u);
    o.y = (__float_as_uint(funmap(c0.z)) >> 16) | (__float_as_uint(funmap(c0.w)) & 0xFFFF0000u);
    o.z = (__float_as_uint(funmap(c1.x)) >> 16) | (__float_as_uint(funmap(c1.y)) & 0xFFFF0000u);
    o.w = (__float_as_uint(funmap(c1.z)) >> 16) | (__float_as_uint(funmap(c1.w)) & 0xFFFF0000u);
    m_pk[n] = o;
}

// Phase C: out[e,h] = exp(t[src,h] - m[tgt,h]) * drop_mask[e,h].
// (Reference's s = segment_max(exp(ef-m)) + 1e-9 == 1.0f exactly in fp32.)
// Slot word g: lo = head g, hi = head g+4.
__global__ __launch_bounds__(256) void finalize_kernel(
    const int* __restrict__ sources, const int* __restrict__ targets,
    const uint4* __restrict__ t_pk4, const uint4* __restrict__ m_pk,
    const float* __restrict__ dm, float* __restrict__ out, int E)
{
    int e = blockIdx.x * 256 + threadIdx.x;
    if (e >= E) return;
    int s  = __builtin_nontemporal_load(sources + e);
    int tg = __builtin_nontemporal_load(targets + e);
    uint4 tv = t_pk4[s];
    uint4 mv = m_pk[tg];
    const vf4* dm4 = (const vf4*)dm;
    vf4 d0 = __builtin_nontemporal_load(dm4 + (size_t)e * 2);      // heads 0..3
    vf4 d1 = __builtin_nontemporal_load(dm4 + (size_t)e * 2 + 1);  // heads 4..7
    vf4 o0, o1;
    o0.x = expf(bf_lo(tv.x) - bf_lo(mv.x)) * d0.x;  // h0
    o0.y = expf(bf_lo(tv.y) - bf_lo(mv.y)) * d0.y;  // h1
    o0.z = expf(bf_lo(tv.z) - bf_lo(mv.z)) * d0.z;  // h2
    o0.w = expf(bf_lo(tv.w) - bf_lo(mv.w)) * d0.w;  // h3
    o1.x = expf(bf_hi(tv.x) - bf_hi(mv.x)) * d1.x;  // h4
    o1.y = expf(bf_hi(tv.y) - bf_hi(mv.y)) * d1.y;  // h5
    o1.z = expf(bf_hi(tv.z) - bf_hi(mv.z)) * d1.z;  // h6
    o1.w = expf(bf_hi(tv.w) - bf_hi(mv.w)) * d1.w;  // h7
    vf4* out4 = (vf4*)out;
    __builtin_nontemporal_store(o0, out4 + (size_t)e * 2);
    __builtin_nontemporal_store(o1, out4 + (size_t)e * 2 + 1);
}

extern "C" void kernel_launch(void* const* d_in, const int* in_sizes, int n_in,
                              void* d_out, int out_size, void* d_ws, size_t ws_size,
                              hipStream_t stream)
{
    const float* X       = (const float*)d_in[0];   // (B,N,H,D) fp32
    const float* Wk      = (const float*)d_in[1];   // (D,H,1)   fp32
    const int*   targets = (const int*)d_in[2];     // (B,E)
    const int*   sources = (const int*)d_in[3];     // (B,E)
    const float* dm      = (const float*)d_in[5];   // (B,E,H)

    int E = in_sizes[2];          // B=1
    int N = in_sizes[4];          // degree is (B,N)

    // Workspace layout: t_pk (N*16 B) | m_u (N*32 B) | m_pk (N*16 B)
    unsigned* t_pk = (unsigned*)d_ws;
    unsigned* m_u  = (unsigned*)d_ws + (size_t)N * 4;
    uint4*    m_pk = (uint4*)((unsigned*)d_ws + (size_t)N * 12);

    float* out = (float*)d_out;

    int blocksA = (N + 7) / 8;           // 4 waves/block, 2 nodes/wave
    attn_tanh_kernel<<<blocksA, 256, 0, stream>>>(X, Wk, t_pk, (uint2*)m_u, N);

    int blocksE = (E + 255) / 256;
    seg_max_kernel<<<blocksE, 256, 0, stream>>>(sources, targets, (const uint4*)t_pk, m_u, E);

    int blocksN = (N + 255) / 256;
    pack_m_kernel<<<blocksN, 256, 0, stream>>>(m_u, m_pk, N);

    finalize_kernel<<<blocksE, 256, 0, stream>>>(sources, targets, (const uint4*)t_pk, m_pk, dm, out, E);
}